// Round 1
// baseline (420.269 us; speedup 1.0000x reference)
//
#include <hip/hip_runtime.h>
#include <math.h>

typedef _Float16 f16;
typedef f16  f16x8 __attribute__((ext_vector_type(8)));
typedef float f32x4 __attribute__((ext_vector_type(4)));

#define MFMA16(a, b, c) __builtin_amdgcn_mfma_f32_16x16x32_f16((a), (b), (c), 0, 0, 0)

// ---------------- workspace layout (f16 element offsets) ----------------
#define W1T_E 0        // [256][480]  vae_W1^T
#define WZV_E 122880   // [48][256]   [vae_Wz | vae_Wv | 0]^T
#define A1T_E 135168   // [64][96]    ae_W1^T
#define A2T_E 141312   // [32][64]    ae_W2^T
#define G1T_E 143360   // [64][32]    gate_W1^T
#define G2T_E 145408   // [16][64]    gate_W2^T (cols 5..15 zero)
#define E1T_E 146432   // [5][128][192] eW1^T, K padded 166->192 with zeros
#define E2T_E 269312   // [5][128][128] eW2^T
#define E3T_E 351232   // [5][32][128]  eW3^T, cols 29..31 zero
#define BZV_B 743424   // byte offset: f32[48] = [vae_bz | vae_bv | 0]

// ---------------- LDS layout (bytes) ----------------
#define O_OFF   0       // [64][8]   f16  o_t term0 (3 cols)
#define Z_OFF   1024    // [64][40]  f16  z_E
#define WGT_OFF 6144    // [64][8]   f32  gate logits -> softmax weights
#define INP_OFF 8192    // [64][200] f16  expert input (built late)
#define ET_OFF  8192    // [64][104] f16  e_t (alias inside INP, dead before INP)
#define HA_OFF  21504   // [64][72]  f16  ae hidden / gate hidden (alias)
#define AB_OFF  33792   // 2 x [64][104] f16 vae-hist frame double buffer
#define H_OFF   47104   // [64][264] f16  vae hidden (overlaps buf1 only, safe)
#define H1_OFF  33792   // [64][136] f16  expert h1 (after INP assembly)
#define H2_OFF  51200   // [64][136] f16  expert h2
#define SMEM_SZ 80896   // < 81920 -> 2 blocks/CU

__device__ __forceinline__ float elu_f(float v) { return v > 0.f ? v : expm1f(v); }

__device__ __forceinline__ f32x4 splat4(float b) {
    f32x4 v; v[0] = b; v[1] = b; v[2] = b; v[3] = b; return v;
}

// source column in x for vae_hist frame f, hist col c (0..95 over terms 1..6)
__device__ __forceinline__ int fsrc(int f, int c) {
    if (c < 9)  { int t = c / 3; return 15 + 15 * t + 3 * f + (c - 3 * t); }
    if (c < 38) return 60  + 29 * f + (c - 9);
    if (c < 67) return 205 + 29 * f + (c - 38);
    return 350 + 29 * f + (c - 67);
}

// ---------------- weight repack: fp32 -> f16, transposed/padded ----------------
__global__ void prep_kernel(const float* __restrict__ vW1, const float* __restrict__ vWz,
                            const float* __restrict__ vWv, const float* __restrict__ aW1,
                            const float* __restrict__ aW2, const float* __restrict__ gW1,
                            const float* __restrict__ gW2, const float* __restrict__ eW1,
                            const float* __restrict__ eW2, const float* __restrict__ eW3,
                            const float* __restrict__ vbz, const float* __restrict__ vbv,
                            char* __restrict__ ws)
{
    int i = blockIdx.x * 256 + threadIdx.x;
    f16* H = (f16*)ws;
    if (i < 122880) {                                   // W1T [c=256][k=480]
        int c = i / 480, k = i - c * 480;
        H[i] = (f16)vW1[k * 256 + c];
    } else if (i < 135168) {                            // WZV [c=48][k=256]
        int j = i - 122880; int c = j / 256, k = j - c * 256;
        float v = (c < 32) ? vWz[k * 32 + c] : ((c < 35) ? vWv[k * 3 + (c - 32)] : 0.f);
        H[i] = (f16)v;
    } else if (i < 141312) {                            // A1T [c=64][k=96]
        int j = i - 135168; int c = j / 96, k = j - c * 96;
        H[i] = (f16)aW1[k * 64 + c];
    } else if (i < 143360) {                            // A2T [c=32][k=64]
        int j = i - 141312; int c = j / 64, k = j - c * 64;
        H[i] = (f16)aW2[k * 32 + c];
    } else if (i < 145408) {                            // G1T [c=64][k=32]
        int j = i - 143360; int c = j / 32, k = j - c * 32;
        H[i] = (f16)gW1[k * 64 + c];
    } else if (i < 146432) {                            // G2T [c=16][k=64]
        int j = i - 145408; int c = j / 64, k = j - c * 64;
        H[i] = (f16)((c < 5) ? gW2[k * 5 + c] : 0.f);
    } else if (i < 269312) {                            // E1T [e][c=128][k=192]
        int j = i - 146432; int e = j / 24576, jj = j - e * 24576;
        int c = jj / 192, k = jj - c * 192;
        H[i] = (f16)((k < 166) ? eW1[(e * 166 + k) * 128 + c] : 0.f);
    } else if (i < 351232) {                            // E2T [e][c=128][k=128]
        int j = i - 269312; int e = j / 16384, jj = j - e * 16384;
        int c = jj / 128, k = jj - c * 128;
        H[i] = (f16)eW2[(e * 128 + k) * 128 + c];
    } else if (i < 371712) {                            // E3T [e][c=32][k=128]
        int j = i - 351232; int e = j / 4096, jj = j - e * 4096;
        int c = jj / 128, k = jj - c * 128;
        H[i] = (f16)((c < 29) ? eW3[(e * 128 + k) * 29 + c] : 0.f);
    } else if (i < 371760) {                            // BZV f32[48]
        int j = i - 371712;
        float v = (j < 32) ? vbz[j] : ((j < 35) ? vbv[j - 32] : 0.f);
        ((float*)(ws + BZV_B))[j] = v;
    }
}

// ---------------- fused actor ----------------
__global__ __launch_bounds__(256, 2) void moe_fused(
    const float* __restrict__ x,
    const float* __restrict__ vb1,
    const float* __restrict__ ab1,
    const float* __restrict__ ab2,
    const float* __restrict__ gb1,
    const float* __restrict__ gb2,
    const float* __restrict__ eb1,
    const float* __restrict__ eb2,
    const float* __restrict__ eb3,
    const char* __restrict__ ws,
    float* __restrict__ out)
{
    __shared__ __align__(16) char smem[SMEM_SZ];
    const int tid  = threadIdx.x;
    const int wv   = tid >> 6;
    const int lane = tid & 63;
    const int lr   = lane & 15;
    const int lg   = lane >> 4;
    const int row0 = (int)blockIdx.x * 64;

    const f16* W1T = (const f16*)ws + W1T_E;
    const f16* WZV = (const f16*)ws + WZV_E;
    const f16* A1T = (const f16*)ws + A1T_E;
    const f16* A2T = (const f16*)ws + A2T_E;
    const f16* G1T = (const f16*)ws + G1T_E;
    const f16* G2T = (const f16*)ws + G2T_E;
    const f16* E1T = (const f16*)ws + E1T_E;
    const f16* E2T = (const f16*)ws + E2T_E;
    const f16* E3T = (const f16*)ws + E3T_E;
    const float* BZV = (const float*)(ws + BZV_B);

    f16*   sO   = (f16*)(smem + O_OFF);
    f16*   sZ   = (f16*)(smem + Z_OFF);
    float* sW   = (float*)(smem + WGT_OFF);
    f16*   sInp = (f16*)(smem + INP_OFF);
    f16*   sEt  = (f16*)(smem + ET_OFF);
    f16*   sHA  = (f16*)(smem + HA_OFF);
    f16*   sAb  = (f16*)(smem + AB_OFF);
    f16*   sH   = (f16*)(smem + H_OFF);
    f16*   sH1  = (f16*)(smem + H1_OFF);
    f16*   sH2  = (f16*)(smem + H2_OFF);

    // ---- phase 0: stage e_t (96 cols) and o_t term0 (3 cols) ----
    for (int idx = tid; idx < 64 * 96; idx += 256) {
        int r = idx / 96, c = idx - r * 96;
        sEt[r * 104 + c] = (f16)x[(row0 + r) * 975 + 879 + c];
    }
    if (tid < 192) {
        int r = tid / 3, c = tid - r * 3;
        sO[r * 8 + c] = (f16)x[(row0 + r) * 975 + 12 + c];
    }
    __syncthreads();

    // ---- G3: ha = elu(e_t @ ae_W1 + ae_b1)  [64x64], K=96. col-split ----
    {
        float b = ab1[16 * wv + lr];
        f32x4 acc[4];
#pragma unroll
        for (int m = 0; m < 4; ++m) acc[m] = splat4(b);
#pragma unroll
        for (int ks = 0; ks < 3; ++ks) {
            f16x8 bf = *(const f16x8*)(A1T + (16 * wv + lr) * 96 + 32 * ks + 8 * lg);
#pragma unroll
            for (int m = 0; m < 4; ++m) {
                f16x8 af = *(const f16x8*)(sEt + (16 * m + lr) * 104 + 32 * ks + 8 * lg);
                acc[m] = MFMA16(af, bf, acc[m]);
            }
        }
#pragma unroll
        for (int m = 0; m < 4; ++m)
#pragma unroll
            for (int r = 0; r < 4; ++r)
                sHA[(16 * m + 4 * lg + r) * 72 + 16 * wv + lr] = (f16)elu_f(acc[m][r]);
    }
    __syncthreads();

    // ---- G4: z_E = ha @ ae_W2 + ae_b2  [64x32], K=64. waves 0,1 ----
    if (wv < 2) {
        float b = ab2[16 * wv + lr];
        f32x4 acc[4];
#pragma unroll
        for (int m = 0; m < 4; ++m) acc[m] = splat4(b);
#pragma unroll
        for (int ks = 0; ks < 2; ++ks) {
            f16x8 bf = *(const f16x8*)(A2T + (16 * wv + lr) * 64 + 32 * ks + 8 * lg);
#pragma unroll
            for (int m = 0; m < 4; ++m) {
                f16x8 af = *(const f16x8*)(sHA + (16 * m + lr) * 72 + 32 * ks + 8 * lg);
                acc[m] = MFMA16(af, bf, acc[m]);
            }
        }
#pragma unroll
        for (int m = 0; m < 4; ++m)
#pragma unroll
            for (int r = 0; r < 4; ++r)
                sZ[(16 * m + 4 * lg + r) * 40 + 16 * wv + lr] = (f16)acc[m][r];
    }
    __syncthreads();

    // ---- gate hidden: gh = elu(z_E @ gate_W1 + gate_b1) [64x64], K=32 ----
    {
        float b = gb1[16 * wv + lr];
        f32x4 acc[4];
#pragma unroll
        for (int m = 0; m < 4; ++m) acc[m] = splat4(b);
        f16x8 bf = *(const f16x8*)(G1T + (16 * wv + lr) * 32 + 8 * lg);
#pragma unroll
        for (int m = 0; m < 4; ++m) {
            f16x8 af = *(const f16x8*)(sZ + (16 * m + lr) * 40 + 8 * lg);
            acc[m] = MFMA16(af, bf, acc[m]);
        }
#pragma unroll
        for (int m = 0; m < 4; ++m)
#pragma unroll
            for (int r = 0; r < 4; ++r)
                sHA[(16 * m + 4 * lg + r) * 72 + 16 * wv + lr] = (f16)elu_f(acc[m][r]);
    }
    __syncthreads();

    // ---- gate logits: gl = gh @ gate_W2 + gate_b2 [64x5], K=64. wave 0 ----
    if (wv == 0) {
        float b = (lr < 5) ? gb2[lr] : 0.f;
        f32x4 acc[4];
#pragma unroll
        for (int m = 0; m < 4; ++m) acc[m] = splat4(b);
#pragma unroll
        for (int ks = 0; ks < 2; ++ks) {
            f16x8 bf = *(const f16x8*)(G2T + lr * 64 + 32 * ks + 8 * lg);
#pragma unroll
            for (int m = 0; m < 4; ++m) {
                f16x8 af = *(const f16x8*)(sHA + (16 * m + lr) * 72 + 32 * ks + 8 * lg);
                acc[m] = MFMA16(af, bf, acc[m]);
            }
        }
        if (lr < 5) {
#pragma unroll
            for (int m = 0; m < 4; ++m)
#pragma unroll
                for (int r = 0; r < 4; ++r)
                    sW[(16 * m + 4 * lg + r) * 8 + lr] = acc[m][r];
        }
    }
    __syncthreads();

    // ---- softmax over 5 (threads 0..63) + stage vae frame 0 (all) ----
    if (tid < 64) {
        float g[5];
#pragma unroll
        for (int e = 0; e < 5; ++e) g[e] = sW[tid * 8 + e];
        float mx = g[0];
#pragma unroll
        for (int e = 1; e < 5; ++e) mx = fmaxf(mx, g[e]);
        float s = 0.f;
#pragma unroll
        for (int e = 0; e < 5; ++e) { g[e] = expf(g[e] - mx); s += g[e]; }
        float inv = 1.f / s;
#pragma unroll
        for (int e = 0; e < 5; ++e) sW[tid * 8 + e] = g[e] * inv;
    }
    for (int idx = tid; idx < 64 * 96; idx += 256) {
        int r = idx / 96, c = idx - r * 96;
        sAb[r * 104 + c] = (f16)x[(row0 + r) * 975 + fsrc(0, c)];
    }
    __syncthreads();

    // ---- G1: h = elu(hist @ vae_W1 + vae_b1) [64x256], K=480 (5 frames) ----
    f32x4 acc1[4][4];
#pragma unroll
    for (int nt = 0; nt < 4; ++nt) {
        float b = vb1[64 * wv + 16 * nt + lr];
#pragma unroll
        for (int m = 0; m < 4; ++m) acc1[m][nt] = splat4(b);
    }
    for (int f = 0; f < 5; ++f) {
        const f16* A = sAb + (f & 1) * (64 * 104);
        float tmp[24];
        if (f < 4) {                       // prefetch next frame into regs
#pragma unroll
            for (int i = 0; i < 24; ++i) {
                int idx = i * 256 + tid;
                int r = idx / 96, c = idx - r * 96;
                tmp[i] = x[(row0 + r) * 975 + fsrc(f + 1, c)];
            }
        }
#pragma unroll
        for (int ks = 0; ks < 3; ++ks) {
            f16x8 bf[4];
#pragma unroll
            for (int nt = 0; nt < 4; ++nt)
                bf[nt] = *(const f16x8*)(W1T + (64 * wv + 16 * nt + lr) * 480 + 96 * f + 32 * ks + 8 * lg);
#pragma unroll
            for (int m = 0; m < 4; ++m) {
                f16x8 af = *(const f16x8*)(A + (16 * m + lr) * 104 + 32 * ks + 8 * lg);
#pragma unroll
                for (int nt = 0; nt < 4; ++nt)
                    acc1[m][nt] = MFMA16(af, bf[nt], acc1[m][nt]);
            }
        }
        if (f < 4) {                       // drain prefetch into other buffer
            f16* D = sAb + ((f + 1) & 1) * (64 * 104);
#pragma unroll
            for (int i = 0; i < 24; ++i) {
                int idx = i * 256 + tid;
                int r = idx / 96, c = idx - r * 96;
                D[r * 104 + c] = (f16)tmp[i];
            }
        }
        __syncthreads();
    }
    // write h (elu, f16). frame4 stays intact in buf0.
#pragma unroll
    for (int m = 0; m < 4; ++m)
#pragma unroll
        for (int nt = 0; nt < 4; ++nt)
#pragma unroll
            for (int r = 0; r < 4; ++r)
                sH[(16 * m + 4 * lg + r) * 264 + 64 * wv + 16 * nt + lr] = (f16)elu_f(acc1[m][nt][r]);
    __syncthreads();

    // ---- G2: [z_H | v_pred] = h @ Wzv + bzv  [64x35], K=256. waves 0..2 ----
    if (wv < 3) {
        float b = BZV[16 * wv + lr];
        f32x4 acc[4];
#pragma unroll
        for (int m = 0; m < 4; ++m) acc[m] = splat4(b);
#pragma unroll
        for (int ks = 0; ks < 8; ++ks) {
            f16x8 bf = *(const f16x8*)(WZV + (16 * wv + lr) * 256 + 32 * ks + 8 * lg);
#pragma unroll
            for (int m = 0; m < 4; ++m) {
                f16x8 af = *(const f16x8*)(sH + (16 * m + lr) * 264 + 32 * ks + 8 * lg);
                acc[m] = MFMA16(af, bf, acc[m]);
            }
        }
        int j = 16 * wv + lr;
#pragma unroll
        for (int m = 0; m < 4; ++m)
#pragma unroll
            for (int r = 0; r < 4; ++r) {
                int row = 16 * m + 4 * lg + r;
                f16 v = (f16)acc[m][r];
                if (j < 32)      sInp[row * 200 + 102 + j] = v;        // z_H
                else if (j < 35) sInp[row * 200 + 99 + (j - 32)] = v;  // v_pred
            }
    }
    // ---- assemble expert input: [o_t(99) | v_pred(3)* | z_H(32)* | z_E(32) | 0(26+)] ----
    if (tid < 192) { int r = tid / 3, c = tid - r * 3; sInp[r * 200 + c] = sO[r * 8 + c]; }
    for (int idx = tid; idx < 64 * 96; idx += 256) {
        int r = idx / 96, c = idx - r * 96;
        sInp[r * 200 + 3 + c] = sAb[r * 104 + c];                       // frame 4 (buf0)
    }
    for (int idx = tid; idx < 64 * 32; idx += 256) {
        int r = idx >> 5, c = idx & 31;
        sInp[r * 200 + 134 + c] = sZ[r * 40 + c];
    }
    for (int idx = tid; idx < 64 * 34; idx += 256) {
        int r = idx / 34, c = idx - r * 34;
        sInp[r * 200 + 166 + c] = (f16)0.f;                             // K-pad zeros
    }
    __syncthreads();

    // ---- experts ----
    f32x4 oacc[2];
    oacc[0] = splat4(0.f); oacc[1] = splat4(0.f);

    for (int e = 0; e < 5; ++e) {
        // L1: h1 = elu(inp @ eW1 + eb1) [64x128], K=192. col-split (2 Nt/wave)
        {
            f32x4 acc[4][2];
#pragma unroll
            for (int nt = 0; nt < 2; ++nt) {
                float b = eb1[e * 128 + 32 * wv + 16 * nt + lr];
#pragma unroll
                for (int m = 0; m < 4; ++m) acc[m][nt] = splat4(b);
            }
#pragma unroll
            for (int ks = 0; ks < 6; ++ks) {
                f16x8 bf[2];
#pragma unroll
                for (int nt = 0; nt < 2; ++nt)
                    bf[nt] = *(const f16x8*)(E1T + (e * 128 + 32 * wv + 16 * nt + lr) * 192 + 32 * ks + 8 * lg);
#pragma unroll
                for (int m = 0; m < 4; ++m) {
                    f16x8 af = *(const f16x8*)(sInp + (16 * m + lr) * 200 + 32 * ks + 8 * lg);
#pragma unroll
                    for (int nt = 0; nt < 2; ++nt) acc[m][nt] = MFMA16(af, bf[nt], acc[m][nt]);
                }
            }
#pragma unroll
            for (int m = 0; m < 4; ++m)
#pragma unroll
                for (int nt = 0; nt < 2; ++nt)
#pragma unroll
                    for (int r = 0; r < 4; ++r)
                        sH1[(16 * m + 4 * lg + r) * 136 + 32 * wv + 16 * nt + lr] = (f16)elu_f(acc[m][nt][r]);
        }
        __syncthreads();
        // L2: h2 = elu(h1 @ eW2 + eb2) [64x128], K=128
        {
            f32x4 acc[4][2];
#pragma unroll
            for (int nt = 0; nt < 2; ++nt) {
                float b = eb2[e * 128 + 32 * wv + 16 * nt + lr];
#pragma unroll
                for (int m = 0; m < 4; ++m) acc[m][nt] = splat4(b);
            }
#pragma unroll
            for (int ks = 0; ks < 4; ++ks) {
                f16x8 bf[2];
#pragma unroll
                for (int nt = 0; nt < 2; ++nt)
                    bf[nt] = *(const f16x8*)(E2T + (e * 128 + 32 * wv + 16 * nt + lr) * 128 + 32 * ks + 8 * lg);
#pragma unroll
                for (int m = 0; m < 4; ++m) {
                    f16x8 af = *(const f16x8*)(sH1 + (16 * m + lr) * 136 + 32 * ks + 8 * lg);
#pragma unroll
                    for (int nt = 0; nt < 2; ++nt) acc[m][nt] = MFMA16(af, bf[nt], acc[m][nt]);
                }
            }
#pragma unroll
            for (int m = 0; m < 4; ++m)
#pragma unroll
                for (int nt = 0; nt < 2; ++nt)
#pragma unroll
                    for (int r = 0; r < 4; ++r)
                        sH2[(16 * m + 4 * lg + r) * 136 + 32 * wv + 16 * nt + lr] = (f16)elu_f(acc[m][nt][r]);
        }
        __syncthreads();
        // L3: acts = h2 @ eW3 + eb3 [64x29(->32)], K=128. row-split (Mt = wave)
        {
            f32x4 acc[2];
#pragma unroll
            for (int nt = 0; nt < 2; ++nt) {
                int col = 16 * nt + lr;
                acc[nt] = splat4((col < 29) ? eb3[e * 29 + col] : 0.f);
            }
#pragma unroll
            for (int ks = 0; ks < 4; ++ks) {
                f16x8 af = *(const f16x8*)(sH2 + (16 * wv + lr) * 136 + 32 * ks + 8 * lg);
#pragma unroll
                for (int nt = 0; nt < 2; ++nt) {
                    f16x8 bf = *(const f16x8*)(E3T + (e * 32 + 16 * nt + lr) * 128 + 32 * ks + 8 * lg);
                    acc[nt] = MFMA16(af, bf, acc[nt]);
                }
            }
#pragma unroll
            for (int r = 0; r < 4; ++r) {
                float wgt = sW[(16 * wv + 4 * lg + r) * 8 + e];
                oacc[0][r] += wgt * acc[0][r];
                oacc[1][r] += wgt * acc[1][r];
            }
        }
        __syncthreads();
    }

    // ---- store out[64x29] fp32 ----
#pragma unroll
    for (int nt = 0; nt < 2; ++nt)
#pragma unroll
        for (int r = 0; r < 4; ++r) {
            int col = 16 * nt + lr;
            if (col < 29) {
                int row = row0 + 16 * wv + 4 * lg + r;
                out[row * 29 + col] = oacc[nt][r];
            }
        }
}

extern "C" void kernel_launch(void* const* d_in, const int* in_sizes, int n_in,
                              void* d_out, int out_size, void* d_ws, size_t ws_size,
                              hipStream_t stream)
{
    (void)n_in; (void)out_size; (void)ws_size;
    const float* x   = (const float*)d_in[0];
    const float* vW1 = (const float*)d_in[1];
    const float* vb1 = (const float*)d_in[2];
    const float* vWz = (const float*)d_in[3];
    const float* vbz = (const float*)d_in[4];
    const float* vWv = (const float*)d_in[5];
    const float* vbv = (const float*)d_in[6];
    const float* aW1 = (const float*)d_in[7];
    const float* ab1 = (const float*)d_in[8];
    const float* aW2 = (const float*)d_in[9];
    const float* ab2 = (const float*)d_in[10];
    const float* gW1 = (const float*)d_in[11];
    const float* gb1 = (const float*)d_in[12];
    const float* gW2 = (const float*)d_in[13];
    const float* gb2 = (const float*)d_in[14];
    const float* eW1 = (const float*)d_in[15];
    const float* eb1 = (const float*)d_in[16];
    const float* eW2 = (const float*)d_in[17];
    const float* eb2 = (const float*)d_in[18];
    const float* eW3 = (const float*)d_in[19];
    const float* eb3 = (const float*)d_in[20];

    int n = in_sizes[0] / 975;

    prep_kernel<<<(371760 + 255) / 256, 256, 0, stream>>>(
        vW1, vWz, vWv, aW1, aW2, gW1, gW2, eW1, eW2, eW3, vbz, vbv, (char*)d_ws);

    moe_fused<<<n / 64, 256, 0, stream>>>(
        x, vb1, ab1, ab2, gb1, gb2, eb1, eb2, eb3, (const char*)d_ws, (float*)d_out);
}

// Round 4
// 319.180 us; speedup vs baseline: 1.3167x; 1.3167x over previous
//
#include <hip/hip_runtime.h>
#include <math.h>

typedef _Float16 f16;
typedef f16  f16x8 __attribute__((ext_vector_type(8)));
typedef float f32x4 __attribute__((ext_vector_type(4)));
typedef unsigned short ushort_t;

#define MFMA16(a, b, c) __builtin_amdgcn_mfma_f32_16x16x32_f16((a), (b), (c), 0, 0, 0)

// ---------------- workspace layout (f16 element offsets) ----------------
#define W1T_E 0        // [256][480]  vae_W1^T
#define WZV_E 122880   // [48][256]   [vae_Wz | vae_Wv | 0]^T
#define A1T_E 135168   // [64][96]    ae_W1^T
#define A2T_E 141312   // [32][64]    ae_W2^T
#define G1T_E 143360   // [64][32]    gate_W1^T
#define G2T_E 145408   // [16][64]    gate_W2^T (cols 5..15 zero)
#define E1T_E 146432   // [5][128][192] eW1^T, K remapped to padded-192 layout
#define E2T_E 269312   // [5][128][128] eW2^T
#define E3T_E 351232   // [5][32][128]  eW3^T, cols 29..31 zero
#define F32_B 743424   // byte offset of f32 appendix:
                       //   [0..47]   BZV  = [vae_bz | vae_bv | 0]
                       //   [48..207] EB3P = eb3 padded [5][32]
                       //   [208..223]GB2P = gate_b2 padded [16]

// ---------------- LDS layout (bytes) ----------------
// buf0 = expert input, K padded to 192 (stride 200):
//   cols 0..4 zero | 5..7 term0(f4) | 8..103 frame(96) | 104..106 v_pred |107 zero
//   | 108..139 z_H | 140..143 zero | 144..175 z_E | 176..191 zero
#define B0_OFF  0       // [64][200] f16 = 25600
#define B1_OFF  25600   // [64][104] f16 = 13312 (odd frames, frame at col 8)
#define ET_OFF  38912   // [64][104] f16 (alias pool; dead after G3)
#define HA_OFF  52224   // [64][72]  f16 (alias pool; dead after gate2)
#define H_OFF   38912   // [64][264] f16 vae hidden (written end of G1)
#define H1_OFF  38912   // [64][136] f16 expert h1 (alias H; after G2)
#define H2_OFF  56320   // [64][136] f16 expert h2
#define W_OFF   73728   // [64][8]   f32 gate weights
#define MAP_OFF 75776   // 96 u32 column map (byte base in x row)
#define SMEM_SZ 76160   // < 81920 -> 2 blocks/CU

__device__ __forceinline__ float elu_f(float v) {
    float e = __expf(v) - 1.f;
    return v > 0.f ? v : e;
}

// round-to-nearest f32x2 -> packed f16x2 (v_cvt_f16_f32 x2 + pack).
__device__ __forceinline__ unsigned pk(float a, float b) {
    ushort_t u0 = __builtin_bit_cast(ushort_t, (f16)a);
    ushort_t u1 = __builtin_bit_cast(ushort_t, (f16)b);
    return (unsigned)u0 | ((unsigned)u1 << 16);
}

__device__ __forceinline__ void store4(f16* p, f32x4 v) {
    uint2 t; t.x = pk(v[0], v[1]); t.y = pk(v[2], v[3]);
    *(uint2*)p = t;
}

__device__ __forceinline__ void elu_store4(f16* p, f32x4 v) {
    uint2 t; t.x = pk(elu_f(v[0]), elu_f(v[1])); t.y = pk(elu_f(v[2]), elu_f(v[3]));
    *(uint2*)p = t;
}

// ---------------- weight repack: fp32 -> f16, transposed/padded ----------------
__global__ void prep_kernel(const float* __restrict__ vW1, const float* __restrict__ vWz,
                            const float* __restrict__ vWv, const float* __restrict__ aW1,
                            const float* __restrict__ aW2, const float* __restrict__ gW1,
                            const float* __restrict__ gW2, const float* __restrict__ eW1,
                            const float* __restrict__ eW2, const float* __restrict__ eW3,
                            const float* __restrict__ vbz, const float* __restrict__ vbv,
                            const float* __restrict__ eb3, const float* __restrict__ gb2,
                            char* __restrict__ ws)
{
    int i = blockIdx.x * 256 + threadIdx.x;
    f16* H = (f16*)ws;
    if (i < 122880) {                                   // W1T [c=256][k=480]
        int c = i / 480, k = i - c * 480;
        H[i] = (f16)vW1[k * 256 + c];
    } else if (i < 135168) {                            // WZV [c=48][k=256]
        int j = i - 122880; int c = j / 256, k = j - c * 256;
        float v = (c < 32) ? vWz[k * 32 + c] : ((c < 35) ? vWv[k * 3 + (c - 32)] : 0.f);
        H[i] = (f16)v;
    } else if (i < 141312) {                            // A1T [c=64][k=96]
        int j = i - 135168; int c = j / 96, k = j - c * 96;
        H[i] = (f16)aW1[k * 64 + c];
    } else if (i < 143360) {                            // A2T [c=32][k=64]
        int j = i - 141312; int c = j / 64, k = j - c * 64;
        H[i] = (f16)aW2[k * 32 + c];
    } else if (i < 145408) {                            // G1T [c=64][k=32]
        int j = i - 143360; int c = j / 32, k = j - c * 32;
        H[i] = (f16)gW1[k * 64 + c];
    } else if (i < 146432) {                            // G2T [c=16][k=64]
        int j = i - 145408; int c = j / 64, k = j - c * 64;
        H[i] = (f16)((c < 5) ? gW2[k * 5 + c] : 0.f);
    } else if (i < 269312) {                            // E1T [e][c=128][k=192] remapped
        int j = i - 146432; int e = j / 24576, jj = j - e * 24576;
        int c = jj / 192, k = jj - c * 192;
        int ko = (k >= 5 && k < 107)   ? (k - 5)
               : (k >= 108 && k < 140) ? (k - 6)
               : (k >= 144 && k < 176) ? (k - 10) : -1;
        H[i] = (f16)((ko >= 0) ? eW1[(e * 166 + ko) * 128 + c] : 0.f);
    } else if (i < 351232) {                            // E2T [e][c=128][k=128]
        int j = i - 269312; int e = j / 16384, jj = j - e * 16384;
        int c = jj / 128, k = jj - c * 128;
        H[i] = (f16)eW2[(e * 128 + k) * 128 + c];
    } else if (i < 371712) {                            // E3T [e][c=32][k=128]
        int j = i - 351232; int e = j / 4096, jj = j - e * 4096;
        int c = jj / 128, k = jj - c * 128;
        H[i] = (f16)((c < 29) ? eW3[(e * 128 + k) * 29 + c] : 0.f);
    } else if (i < 371936) {                            // f32 appendix
        int j = i - 371712;
        float* F = (float*)(ws + F32_B);
        float v;
        if (j < 48)       v = (j < 32) ? vbz[j] : ((j < 35) ? vbv[j - 32] : 0.f);
        else if (j < 208) { int t = j - 48; int e = t >> 5, c = t & 31;
                            v = (c < 29) ? eb3[e * 29 + c] : 0.f; }
        else              { int t = j - 208; v = (t < 5) ? gb2[t] : 0.f; }
        F[j] = v;
    }
}

// ---------------- fused actor ----------------
__global__ __launch_bounds__(256, 2) void moe_fused(
    const float* __restrict__ x,
    const float* __restrict__ vb1,
    const float* __restrict__ ab1,
    const float* __restrict__ ab2,
    const float* __restrict__ gb1,
    const float* __restrict__ eb1,
    const float* __restrict__ eb2,
    const char* __restrict__ ws,
    float* __restrict__ out)
{
    __shared__ __align__(16) char smem[SMEM_SZ];
    const int tid  = threadIdx.x;
    const int wv   = tid >> 6;
    const int lane = tid & 63;
    const int lr   = lane & 15;
    const int lg   = lane >> 4;
    const int row0 = (int)blockIdx.x * 64;

    const f16* W1T = (const f16*)ws + W1T_E;
    const f16* WZV = (const f16*)ws + WZV_E;
    const f16* A1T = (const f16*)ws + A1T_E;
    const f16* A2T = (const f16*)ws + A2T_E;
    const f16* G1T = (const f16*)ws + G1T_E;
    const f16* G2T = (const f16*)ws + G2T_E;
    const f16* E1T = (const f16*)ws + E1T_E;
    const f16* E2T = (const f16*)ws + E2T_E;
    const f16* E3T = (const f16*)ws + E3T_E;
    const float* BZV  = (const float*)(ws + F32_B);
    const float* EB3P = BZV + 48;
    const float* GB2P = BZV + 208;

    f16* sB0 = (f16*)(smem + B0_OFF);
    f16* sB1 = (f16*)(smem + B1_OFF);
    f16* sEt = (f16*)(smem + ET_OFF);
    f16* sHA = (f16*)(smem + HA_OFF);
    f16* sH  = (f16*)(smem + H_OFF);
    f16* sH1 = (f16*)(smem + H1_OFF);
    f16* sH2 = (f16*)(smem + H2_OFF);
    float* sWf = (float*)(smem + W_OFF);
    unsigned* smap = (unsigned*)(smem + MAP_OFF);

    const char* xc = (const char*)x;
    const int srow = tid >> 2;            // staging row 0..63
    const int cb   = 24 * (tid & 3);      // staging col base (of 96)
    const bool lowc = ((tid & 3) == 0);

    // ---- phase 0: srcmap, zero-init buf0 special cols, term0, e_t ----
    if (tid < 96) {
        int c = tid; int base;
        if (c < 9)       { int t = c / 3; base = 15 + 12 * t + c; }
        else if (c < 38) base = 51 + c;
        else if (c < 67) base = 167 + c;
        else             base = 283 + c;
        smap[c] = (unsigned)(base * 4);
    }
    if (tid < 64) {
        f16* rp = sB0 + tid * 200;
        uint2 z2; z2.x = 0u; z2.y = 0u;
        *(uint2*)(rp + 0) = z2; rp[4] = (f16)0.f;       // cols 0..4
        *(uint2*)(rp + 140) = z2;                       // cols 140..143
        uint4 z4; z4.x = z4.y = z4.z = z4.w = 0u;
        *(uint4*)(rp + 176) = z4; *(uint4*)(rp + 184) = z4; // cols 176..191
    }
    if (tid < 192) {
        int r = tid / 3, c = tid - 3 * r;
        sB0[r * 200 + 5 + c] = (f16)x[(row0 + r) * 975 + 12 + c];
    }
    {   // e_t -> sEt  (rows tid>>2, 24 cols each, pk-paired b32 writes)
        const float* xr = x + (size_t)(row0 + srow) * 975 + 879 + cb;
        f16* dst = sEt + srow * 104 + cb;
#pragma unroll
        for (int k = 0; k < 24; k += 2) {
            *(unsigned*)(dst + k) = pk(xr[k], xr[k + 1]);
        }
    }
    __syncthreads();

    // ---- G3: ha = elu(e_t @ ae_W1 + ae_b1)  [64 rows x 64 cols], K=96 ----
    {
        f32x4 bi = *(const f32x4*)(ab1 + 16 * wv + 4 * lg);
        f32x4 acc[4];
#pragma unroll
        for (int m = 0; m < 4; ++m) acc[m] = bi;
#pragma unroll
        for (int ks = 0; ks < 3; ++ks) {
            f16x8 wf = *(const f16x8*)(A1T + (16 * wv + lr) * 96 + 32 * ks + 8 * lg);
#pragma unroll
            for (int m = 0; m < 4; ++m) {
                f16x8 bf = *(const f16x8*)(sEt + (16 * m + lr) * 104 + 32 * ks + 8 * lg);
                acc[m] = MFMA16(wf, bf, acc[m]);
            }
        }
#pragma unroll
        for (int m = 0; m < 4; ++m)
            elu_store4(sHA + (16 * m + lr) * 72 + 16 * wv + 4 * lg, acc[m]);
    }
    // init staging offsets (srcmap written phase 0, synced)
    unsigned a_off[24];
    {
        unsigned rowb = (unsigned)(row0 + srow) * 3900u;
#pragma unroll
        for (int i = 0; i < 24; ++i) a_off[i] = rowb + smap[cb + i];
    }
    __syncthreads();

    // ---- phase A: G4 (waves 0,1) + stage frame0 -> buf0 (all threads) ----
    if (wv < 2) {
        f32x4 bi = *(const f32x4*)(ab2 + 16 * wv + 4 * lg);
        f32x4 acc[4];
#pragma unroll
        for (int m = 0; m < 4; ++m) acc[m] = bi;
#pragma unroll
        for (int ks = 0; ks < 2; ++ks) {
            f16x8 wf = *(const f16x8*)(A2T + (16 * wv + lr) * 64 + 32 * ks + 8 * lg);
#pragma unroll
            for (int m = 0; m < 4; ++m) {
                f16x8 bf = *(const f16x8*)(sHA + (16 * m + lr) * 72 + 32 * ks + 8 * lg);
                acc[m] = MFMA16(wf, bf, acc[m]);
            }
        }
#pragma unroll
        for (int m = 0; m < 4; ++m)   // z_E (raw, no elu) -> buf0 cols 144..175
            store4(sB0 + (16 * m + lr) * 200 + 144 + 16 * wv + 4 * lg, acc[m]);
    }
    {   // frame 0 -> buf0 cols 8..103
        float tv[24];
#pragma unroll
        for (int i = 0; i < 24; ++i) tv[i] = *(const float*)(xc + a_off[i]);
        f16* dst = sB0 + srow * 200 + 8 + cb;
#pragma unroll
        for (int k = 0; k < 12; ++k) *(unsigned*)(dst + 2 * k) = pk(tv[2 * k], tv[2 * k + 1]);
#pragma unroll
        for (int i = 0; i < 24; ++i) a_off[i] += (lowc && i < 9) ? 12u : 116u;
    }
    __syncthreads();

    // ---- gate hidden: gh = elu(z_E @ gate_W1 + gate_b1) [64x64], K=32 ----
    {
        f32x4 bi = *(const f32x4*)(gb1 + 16 * wv + 4 * lg);
        f32x4 acc[4];
#pragma unroll
        for (int m = 0; m < 4; ++m) acc[m] = bi;
        f16x8 wf = *(const f16x8*)(G1T + (16 * wv + lr) * 32 + 8 * lg);
#pragma unroll
        for (int m = 0; m < 4; ++m) {
            f16x8 bf = *(const f16x8*)(sB0 + (16 * m + lr) * 200 + 144 + 8 * lg);
            acc[m] = MFMA16(wf, bf, acc[m]);
        }
#pragma unroll
        for (int m = 0; m < 4; ++m)
            elu_store4(sHA + (16 * m + lr) * 72 + 16 * wv + 4 * lg, acc[m]);
    }
    __syncthreads();

    // ---- gate logits (wave 0): gl = gh @ gate_W2 + gate_b2 -> sWf ----
    // D row i = 4*lg + r = logit column; only cols 0..4 are real.
    // Guard: lg==0 writes cols 0..3; lg==1 writes col 4 only.
    // (R2/R3 bug: unguarded lg=2,3 stores spilled into the NEXT row's
    //  logits with zeros -> gating race -> absmax 1.2e-2.)
    if (wv == 0) {
        f32x4 bi = *(const f32x4*)(GB2P + 4 * lg);
        f32x4 acc[4];
#pragma unroll
        for (int m = 0; m < 4; ++m) acc[m] = bi;
#pragma unroll
        for (int ks = 0; ks < 2; ++ks) {
            f16x8 wf = *(const f16x8*)(G2T + lr * 64 + 32 * ks + 8 * lg);
#pragma unroll
            for (int m = 0; m < 4; ++m) {
                f16x8 bf = *(const f16x8*)(sHA + (16 * m + lr) * 72 + 32 * ks + 8 * lg);
                acc[m] = MFMA16(wf, bf, acc[m]);
            }
        }
        if (lg == 0) {
#pragma unroll
            for (int m = 0; m < 4; ++m)
                *(f32x4*)(sWf + (16 * m + lr) * 8) = acc[m];
        } else if (lg == 1) {
#pragma unroll
            for (int m = 0; m < 4; ++m)
                sWf[(16 * m + lr) * 8 + 4] = acc[m][0];
        }
    }
    __syncthreads();

    // ---- G1: h = elu(hist @ vae_W1 + vae_b1) [64 x 256], K=480 (5 frames) ----
    f32x4 acc1[4][4];
#pragma unroll
    for (int nt = 0; nt < 4; ++nt) {
        f32x4 bi = *(const f32x4*)(vb1 + 64 * wv + 16 * nt + 4 * lg);
#pragma unroll
        for (int m = 0; m < 4; ++m) acc1[m][nt] = bi;
    }
    for (int f = 0; f < 5; ++f) {
        if (f == 0 && tid < 64) {     // softmax over 5 gate logits
            float g[5];
#pragma unroll
            for (int e = 0; e < 5; ++e) g[e] = sWf[tid * 8 + e];
            float mx = fmaxf(fmaxf(fmaxf(g[0], g[1]), fmaxf(g[2], g[3])), g[4]);
            float s = 0.f;
#pragma unroll
            for (int e = 0; e < 5; ++e) { g[e] = __expf(g[e] - mx); s += g[e]; }
            float inv = 1.f / s;
#pragma unroll
            for (int e = 0; e < 5; ++e) sWf[tid * 8 + e] = g[e] * inv;
        }
        float tv[24];
        if (f < 4) {
#pragma unroll
            for (int i = 0; i < 24; ++i) tv[i] = *(const float*)(xc + a_off[i]);
        }
        const f16* Bp = (f & 1) ? sB1 : sB0;
        const int bst = (f & 1) ? 104 : 200;
#pragma unroll
        for (int ks = 0; ks < 3; ++ks) {
            f16x8 wf[4];
#pragma unroll
            for (int nt = 0; nt < 4; ++nt)
                wf[nt] = *(const f16x8*)(W1T + (64 * wv + 16 * nt + lr) * 480 + 96 * f + 32 * ks + 8 * lg);
#pragma unroll
            for (int m = 0; m < 4; ++m) {
                f16x8 bf = *(const f16x8*)(Bp + (16 * m + lr) * bst + 8 + 32 * ks + 8 * lg);
#pragma unroll
                for (int nt = 0; nt < 4; ++nt)
                    acc1[m][nt] = MFMA16(wf[nt], bf, acc1[m][nt]);
            }
        }
        if (f < 4) {                  // drain frame f+1 into the other buffer
            f16* dst = (((f + 1) & 1) ? sB1 : sB0) + srow * (((f + 1) & 1) ? 104 : 200) + 8 + cb;
#pragma unroll
            for (int k = 0; k < 12; ++k) *(unsigned*)(dst + 2 * k) = pk(tv[2 * k], tv[2 * k + 1]);
#pragma unroll
            for (int i = 0; i < 24; ++i) a_off[i] += (lowc && i < 9) ? 12u : 116u;
        }
        if (f == 4) {                 // write h (elu) -> sH
#pragma unroll
            for (int m = 0; m < 4; ++m)
#pragma unroll
                for (int nt = 0; nt < 4; ++nt)
                    elu_store4(sH + (16 * m + lr) * 264 + 64 * wv + 16 * nt + 4 * lg, acc1[m][nt]);
        }
        __syncthreads();
    }

    // ---- G2: [v_pred|z_H] = h @ Wzv + bzv, K=256, waves 0..2 -> buf0 ----
    if (wv < 3) {
        f32x4 bz = *(const f32x4*)(BZV + 16 * wv + 4 * lg);
        f32x4 acc[4];
#pragma unroll
        for (int m = 0; m < 4; ++m) acc[m] = bz;
#pragma unroll
        for (int ks = 0; ks < 8; ++ks) {
            f16x8 wf = *(const f16x8*)(WZV + (16 * wv + lr) * 256 + 32 * ks + 8 * lg);
#pragma unroll
            for (int m = 0; m < 4; ++m) {
                f16x8 bf = *(const f16x8*)(sH + (16 * m + lr) * 264 + 32 * ks + 8 * lg);
                acc[m] = MFMA16(wf, bf, acc[m]);
            }
        }
        int j0 = 16 * wv + 4 * lg;
        if (wv < 2 || lg == 0) {
            int col = (wv < 2) ? (108 + j0) : 104;   // z_H at 108.., v_pred at 104..107
#pragma unroll
            for (int m = 0; m < 4; ++m)
                store4(sB0 + (16 * m + lr) * 200 + col, acc[m]);
        }
    }
    __syncthreads();

    // ---- experts: 5 x (L1 K=192, L2 K=128, L3 K=128) ----
    f32x4 oacc[2];
    oacc[0] = (f32x4)0.f; oacc[1] = (f32x4)0.f;

    for (int e = 0; e < 5; ++e) {
        // L1: h1 = elu(inp @ eW1 + eb1): 32 cols/wave
        {
            f32x4 acc[4][2];
#pragma unroll
            for (int nt = 0; nt < 2; ++nt) {
                f32x4 bi = *(const f32x4*)(eb1 + e * 128 + 32 * wv + 16 * nt + 4 * lg);
#pragma unroll
                for (int m = 0; m < 4; ++m) acc[m][nt] = bi;
            }
#pragma unroll
            for (int ks = 0; ks < 6; ++ks) {
                f16x8 wf[2];
#pragma unroll
                for (int nt = 0; nt < 2; ++nt)
                    wf[nt] = *(const f16x8*)(E1T + (e * 128 + 32 * wv + 16 * nt + lr) * 192 + 32 * ks + 8 * lg);
#pragma unroll
                for (int m = 0; m < 4; ++m) {
                    f16x8 bf = *(const f16x8*)(sB0 + (16 * m + lr) * 200 + 32 * ks + 8 * lg);
#pragma unroll
                    for (int nt = 0; nt < 2; ++nt) acc[m][nt] = MFMA16(wf[nt], bf, acc[m][nt]);
                }
            }
#pragma unroll
            for (int m = 0; m < 4; ++m)
#pragma unroll
                for (int nt = 0; nt < 2; ++nt)
                    elu_store4(sH1 + (16 * m + lr) * 136 + 32 * wv + 16 * nt + 4 * lg, acc[m][nt]);
        }
        __syncthreads();
        // L2: h2 = elu(h1 @ eW2 + eb2)
        {
            f32x4 acc[4][2];
#pragma unroll
            for (int nt = 0; nt < 2; ++nt) {
                f32x4 bi = *(const f32x4*)(eb2 + e * 128 + 32 * wv + 16 * nt + 4 * lg);
#pragma unroll
                for (int m = 0; m < 4; ++m) acc[m][nt] = bi;
            }
#pragma unroll
            for (int ks = 0; ks < 4; ++ks) {
                f16x8 wf[2];
#pragma unroll
                for (int nt = 0; nt < 2; ++nt)
                    wf[nt] = *(const f16x8*)(E2T + (e * 128 + 32 * wv + 16 * nt + lr) * 128 + 32 * ks + 8 * lg);
#pragma unroll
                for (int m = 0; m < 4; ++m) {
                    f16x8 bf = *(const f16x8*)(sH1 + (16 * m + lr) * 136 + 32 * ks + 8 * lg);
#pragma unroll
                    for (int nt = 0; nt < 2; ++nt) acc[m][nt] = MFMA16(wf[nt], bf, acc[m][nt]);
                }
            }
#pragma unroll
            for (int m = 0; m < 4; ++m)
#pragma unroll
                for (int nt = 0; nt < 2; ++nt)
                    elu_store4(sH2 + (16 * m + lr) * 136 + 32 * wv + 16 * nt + 4 * lg, acc[m][nt]);
        }
        __syncthreads();
        // L3: acts = h2 @ eW3 + eb3 ; weight and accumulate. rows 16*wv..
        {
            f32x4 acc3[2];
#pragma unroll
            for (int nt = 0; nt < 2; ++nt)
                acc3[nt] = *(const f32x4*)(EB3P + e * 32 + 16 * nt + 4 * lg);
#pragma unroll
            for (int ks = 0; ks < 4; ++ks) {
                f16x8 bf = *(const f16x8*)(sH2 + (16 * wv + lr) * 136 + 32 * ks + 8 * lg);
#pragma unroll
                for (int nt = 0; nt < 2; ++nt) {
                    f16x8 wf = *(const f16x8*)(E3T + (e * 32 + 16 * nt + lr) * 128 + 32 * ks + 8 * lg);
                    acc3[nt] = MFMA16(wf, bf, acc3[nt]);
                }
            }
            float we = sWf[(16 * wv + lr) * 8 + e];
#pragma unroll
            for (int nt = 0; nt < 2; ++nt)
#pragma unroll
                for (int r = 0; r < 4; ++r) oacc[nt][r] += we * acc3[nt][r];
        }
        __syncthreads();
    }

    // ---- store out [64 x 29] fp32: lane holds row (16wv+lr), 4-col groups ----
    {
        int row = row0 + 16 * wv + lr;
#pragma unroll
        for (int nt = 0; nt < 2; ++nt)
#pragma unroll
            for (int r = 0; r < 4; ++r) {
                int col = 16 * nt + 4 * lg + r;
                if (col < 29) out[row * 29 + col] = oacc[nt][r];
            }
    }
}

extern "C" void kernel_launch(void* const* d_in, const int* in_sizes, int n_in,
                              void* d_out, int out_size, void* d_ws, size_t ws_size,
                              hipStream_t stream)
{
    (void)n_in; (void)out_size; (void)ws_size;
    const float* x   = (const float*)d_in[0];
    const float* vW1 = (const float*)d_in[1];
    const float* vb1 = (const float*)d_in[2];
    const float* vWz = (const float*)d_in[3];
    const float* vbz = (const float*)d_in[4];
    const float* vWv = (const float*)d_in[5];
    const float* vbv = (const float*)d_in[6];
    const float* aW1 = (const float*)d_in[7];
    const float* ab1 = (const float*)d_in[8];
    const float* aW2 = (const float*)d_in[9];
    const float* ab2 = (const float*)d_in[10];
    const float* gW1 = (const float*)d_in[11];
    const float* gb1 = (const float*)d_in[12];
    const float* gW2 = (const float*)d_in[13];
    const float* gb2 = (const float*)d_in[14];
    const float* eW1 = (const float*)d_in[15];
    const float* eb1 = (const float*)d_in[16];
    const float* eW2 = (const float*)d_in[17];
    const float* eb2 = (const float*)d_in[18];
    const float* eW3 = (const float*)d_in[19];
    const float* eb3 = (const float*)d_in[20];

    int n = in_sizes[0] / 975;

    prep_kernel<<<(371936 + 255) / 256, 256, 0, stream>>>(
        vW1, vWz, vWv, aW1, aW2, gW1, gW2, eW1, eW2, eW3, vbz, vbv, eb3, gb2, (char*)d_ws);

    moe_fused<<<n / 64, 256, 0, stream>>>(
        x, vb1, ab1, ab2, gb1, eb1, eb2, (const char*)d_ws, (float*)d_out);
}